// Round 3
// baseline (19353.281 us; speedup 1.0000x reference)
//
#include <hip/hip_runtime.h>
#include <hip/hip_bf16.h>
#include <stdint.h>

// Problem sizes (fixed)
#define NB 512     // batch
#define NS 256     // source length
#define ND 256     // hidden dim
#define NT 256     // decode steps
#define NO 3       // output dim

#define LOG2E 1.44269504088896340736f
#define C2 (2.0f*LOG2E)

#if __has_builtin(__builtin_amdgcn_exp2f)
__device__ __forceinline__ float exp2_fast(float x){ return __builtin_amdgcn_exp2f(x); }
#else
__device__ __forceinline__ float exp2_fast(float x){ return exp2f(x); }
#endif
#if __has_builtin(__builtin_amdgcn_rcpf)
__device__ __forceinline__ float rcp_fast(float x){ return __builtin_amdgcn_rcpf(x); }
#else
__device__ __forceinline__ float rcp_fast(float x){ return 1.0f/x; }
#endif

__device__ __forceinline__ float tanh_f(float x){
  float e = exp2_fast(x * C2);
  return 1.0f - 2.0f*rcp_fast(e + 1.0f);
}
// tanh with pre-scaled argument z = x * 2*log2e
__device__ __forceinline__ float tanh_pre(float z){
  return 1.0f - 2.0f*rcp_fast(exp2_fast(z) + 1.0f);
}
__device__ __forceinline__ float sigm_f(float x){
  return rcp_fast(1.0f + exp2_fast(-x*LOG2E));
}
__device__ __forceinline__ float bflo(uint32_t u){ return __uint_as_float(u<<16); }
__device__ __forceinline__ float bfhi(uint32_t u){ return __uint_as_float(u & 0xffff0000u); }
__device__ __forceinline__ uint16_t f2bf(float f){   // round-to-nearest-even bf16
  uint32_t u = __float_as_uint(f);
  return (uint16_t)((u + 0x7fffu + ((u>>16)&1u)) >> 16);
}
__device__ __forceinline__ uint32_t pack2(float a, float b){
  return (uint32_t)f2bf(a) | ((uint32_t)f2bf(b) << 16);
}

// bf16-pair dot product: c + a.lo*b.lo + a.hi*b.hi
#if __has_builtin(__builtin_amdgcn_fdot2_f32_bf16)
typedef __bf16 bfp2 __attribute__((ext_vector_type(2)));
__device__ __forceinline__ float dot2bf(uint32_t a, uint32_t b, float c){
  return __builtin_amdgcn_fdot2_f32_bf16(__builtin_bit_cast(bfp2, a),
                                         __builtin_bit_cast(bfp2, b), c, false);
}
#else
__device__ __forceinline__ float dot2bf(uint32_t a, uint32_t b, float c){
  return c + bflo(a)*bflo(b) + bfhi(a)*bfhi(b);
}
#endif

// ---------------- prep kernels ----------------

// dst[c*R + r] = src[r*C + c]
__global__ void k_transpose(const float* __restrict__ src, float* __restrict__ dst,
                            int R, int C){
  int idx = blockIdx.x*256 + threadIdx.x;
  if (idx < R*C){
    int r = idx / C, c = idx - r*C;
    dst[c*R + r] = src[idx];
  }
}

// UK[b][e4][s][4] (bf16, d-interleaved-by-4, PRE-SCALED by 2*log2e)
__global__ void __launch_bounds__(256) k_uk(const float* __restrict__ e_all,
    const float* __restrict__ UaT, const float* __restrict__ bu,
    uint16_t* __restrict__ UK){
  __shared__ float At[ND][20];
  const int t = threadIdx.x;
  const int m0 = blockIdx.x * 16;
  const int b  = m0 >> 8;
  const int s0 = m0 & (NS-1);
  #pragma unroll
  for (int i=0;i<16;i++)
    At[t][i] = e_all[(size_t)(m0+i)*ND + t];
  __syncthreads();
  float acc[16];
  float bue = bu[t];
  #pragma unroll
  for (int i=0;i<16;i++) acc[i] = bue;
  for (int d=0; d<ND; ++d){
    float u = UaT[d*ND + t];
    const float4 a0 = *(const float4*)&At[d][0];
    const float4 a1 = *(const float4*)&At[d][4];
    const float4 a2 = *(const float4*)&At[d][8];
    const float4 a3 = *(const float4*)&At[d][12];
    acc[0]+=a0.x*u;  acc[1]+=a0.y*u;  acc[2]+=a0.z*u;  acc[3]+=a0.w*u;
    acc[4]+=a1.x*u;  acc[5]+=a1.y*u;  acc[6]+=a1.z*u;  acc[7]+=a1.w*u;
    acc[8]+=a2.x*u;  acc[9]+=a2.y*u;  acc[10]+=a2.z*u; acc[11]+=a2.w*u;
    acc[12]+=a3.x*u; acc[13]+=a3.y*u; acc[14]+=a3.z*u; acc[15]+=a3.w*u;
  }
  const int e4 = t>>2, j = t&3;
  uint16_t* base = UK + (size_t)b*NS*ND + (size_t)e4*(NS*4) + j;
  #pragma unroll
  for (int i=0;i<16;i++)
    base[(size_t)(s0+i)*4] = f2bf(acc[i] * C2);
}

// EP[b][s2][d] = {bf16 e[b][2s2][d], bf16 e[b][2s2+1][d]}
__global__ void k_ep(const float* __restrict__ e_all, uint32_t* __restrict__ EP){
  int idx = blockIdx.x*256 + threadIdx.x;
  if (idx >= NB*128*256) return;
  int d  = idx & 255;
  int s2 = (idx >> 8) & 127;
  int b  = idx >> 15;
  float e0 = e_all[((size_t)b*NS + 2*s2  )*ND + d];
  float e1 = e_all[((size_t)b*NS + 2*s2+1)*ND + d];
  EP[idx] = pack2(e0, e1);
}

// PKq[k2][g][d] u32 pairs over combined K-axis:
//   k2 in [0,130): x-part pairs {k=2k2, 2k2+1} of W_ih (k<259, else 0)
//   k2 in [130,258): h-part pairs {kk=2(k2-130), +1} of W_hh
//   k2 in [258,260): zero pad
__global__ void k_pkq(const float* __restrict__ W_ih, const float* __restrict__ W_hh,
                      uint32_t* __restrict__ PKq){
  int idx = blockIdx.x*256 + threadIdx.x;   // ((k2*3)+g)*256 + d
  if (idx >= 260*3*256) return;
  int d  = idx & 255;
  int gk = idx >> 8;
  int k2 = gk/3, g = gk - 3*k2;
  int col = g*256 + d;
  float w0 = 0.f, w1 = 0.f;
  if (k2 < 130){
    int k0 = 2*k2, k1 = k0+1;
    w0 = W_ih[(size_t)col*259 + k0];
    w1 = (k1 < 259) ? W_ih[(size_t)col*259 + k1] : 0.f;
  } else if (k2 < 258){
    int kk = 2*(k2-130);
    w0 = W_hh[(size_t)col*256 + kk];
    w1 = W_hh[(size_t)col*256 + kk+1];
  }
  PKq[idx] = pack2(w0, w1);
}

// PQ[k2][d] = {bf16 Wa[d][2k2], bf16 Wa[d][2k2+1]}
__global__ void k_pack_q(const float* __restrict__ Wa, uint32_t* __restrict__ PQ){
  int idx = blockIdx.x*256 + threadIdx.x;   // k2*256 + d
  if (idx >= 128*256) return;
  int d = idx & 255, k2 = idx >> 8;
  PQ[idx] = pack2(Wa[(size_t)d*256 + 2*k2], Wa[(size_t)d*256 + 2*k2 + 1]);
}

// ---------------- persistent decode kernel ----------------
// 1024 threads (16 waves) per block, one batch element per block.
// d = t&255 (output index), q4 = t>>8 (K-quarter), w = t>>6 (wave).
__global__ void __launch_bounds__(1024, 8) k_decode(
    const uint16_t* __restrict__ UK, const uint32_t* __restrict__ EP,
    const uint32_t* __restrict__ PKq, const uint32_t* __restrict__ PQ,
    const float* __restrict__ e_last,
    const float* __restrict__ Va, const float* __restrict__ bv,
    const float* __restrict__ b_ih, const float* __restrict__ b_hh,
    const float* __restrict__ ba, const float* __restrict__ bo,
    const float* __restrict__ Wo,
    float* __restrict__ dout, float* __restrict__ hT_out, float* __restrict__ ca)
{
  __shared__ float    hf[ND];              // h (f32)
  __shared__ float    xin[4];              // autoregressive x_in
  __shared__ uint32_t xb[260];             // bf16-pair input vec (k2-indexed): [0..129]=ctx+x, [130..257]=h
  __shared__ __align__(16) float qL[ND];   // pre-scaled q
  __shared__ __align__(16) float VaL[ND];
  __shared__ float    WoL[3*ND];
  __shared__ float    qpart[4][ND];
  __shared__ float    spart[4][ND];
  __shared__ __align__(16) float cpart[16][ND];
  __shared__ float    gpart[12][ND];       // [q4*3+g][d]
  __shared__ uint32_t wb[128];             // bf16-pair softmax weights over s-pairs
  __shared__ float    red[16];

  const int t    = threadIdx.x;
  const int d    = t & 255;
  const int q4   = t >> 8;
  const int lane = t & 63;
  const int w    = t >> 6;
  const int b    = blockIdx.x;

  // ---- init ----
  if (q4 == 0){
    hf[d]  = e_last[(size_t)b*ND + d];
    VaL[d] = Va[d];
    WoL[d] = Wo[d]; WoL[256+d] = Wo[256+d]; WoL[512+d] = Wo[512+d];
    if (d < 4) xin[d] = 0.f;
  }
  const float bias_r  = b_ih[d]     + b_hh[d];
  const float bias_z  = b_ih[256+d] + b_hh[256+d];
  const float bias_ni = b_ih[512+d];
  const float bias_nh = b_hh[512+d];
  const float ba_d = ba[d];
  const float bv0  = bv[0];
  const float bo0 = bo[0], bo1 = bo[1], bo2 = bo[2];
  __syncthreads();
  if (t < 128) xb[130+t] = pack2(hf[2*t], hf[2*t+1]);
  if (t == 128){ xb[128]=0u; xb[129]=0u; xb[258]=0u; xb[259]=0u; }
  __syncthreads();

  const uint16_t* ukb = UK + (size_t)b*NS*ND;
  const uint32_t* epb = EP + (size_t)b*128*256;
  float* ca_b = ca   + (size_t)b*(NT*NS);
  float* do_b = dout + (size_t)b*(NT*NO);

  for (int step=0; step<NT; ++step){
    // ---- Q: q = h @ Wa^T + ba (4-way K-split, dot2) ----
    {
      float aq = (q4==0) ? ba_d : 0.f;
      const int k0 = q4*32;
      #pragma unroll 8
      for (int k2=k0; k2<k0+32; ++k2)
        aq = dot2bf(PQ[k2*256 + d], xb[130+k2], aq);
      qpart[q4][d] = aq;
    }
    __syncthreads();
    if (q4 == 0)
      qL[d] = ((qpart[0][d]+qpart[1][d]) + (qpart[2][d]+qpart[3][d])) * C2;
    __syncthreads();

    // ---- S: scores, s=d, quarter over e4 (pre-scaled tanh) ----
    {
      float acc = 0.f;
      const int e0 = q4*16;
      #pragma unroll 4
      for (int e4=e0; e4<e0+16; ++e4){
        uint2 u = *(const uint2*)(ukb + (size_t)e4*(NS*4) + d*4);
        const float4 qq = *(const float4*)&qL[e4*4];
        const float4 vv = *(const float4*)&VaL[e4*4];
        acc = fmaf(tanh_pre(bflo(u.x)+qq.x), vv.x, acc);
        acc = fmaf(tanh_pre(bfhi(u.x)+qq.y), vv.y, acc);
        acc = fmaf(tanh_pre(bflo(u.y)+qq.z), vv.z, acc);
        acc = fmaf(tanh_pre(bfhi(u.y)+qq.w), vv.w, acc);
      }
      spart[q4][d] = acc;
    }
    __syncthreads();
    // softmax without max-subtract: |score| <= sum|Va|+|bv| ~ 13, exp2 safe in f32
    float p_reg = 0.f;
    if (q4 == 0){
      float sc = (spart[0][d]+spart[1][d]) + (spart[2][d]+spart[3][d]) + bv0;
      p_reg = exp2_fast(sc * LOG2E);
      float ssum = p_reg;
      #pragma unroll
      for (int o=32;o;o>>=1) ssum += __shfl_xor(ssum, o);
      if (lane==0) red[w] = ssum;
    }
    __syncthreads();
    if (q4 == 0){
      float ssum = (red[0]+red[1]) + (red[2]+red[3]);
      float wgt = p_reg * rcp_fast(ssum);
      __builtin_nontemporal_store(wgt, &ca_b[(size_t)step*NS + d]);
      float other = __shfl_xor(wgt, 1);
      if ((d & 1) == 0) wb[d>>1] = pack2(wgt, other);
    }
    __syncthreads();

    // ---- C: ctx via dot2 over s-pairs; wave w owns s2 in [w*8, w*8+8) ----
    {
      float c0=0,c1=0,c2=0,c3=0;
      const int s0 = w*8;
      #pragma unroll
      for (int i=0;i<8;i++){
        int s2 = s0+i;
        uint32_t wp = wb[s2];
        uint4 ev = *(const uint4*)(epb + (size_t)s2*256 + lane*4);
        c0 = dot2bf(ev.x, wp, c0);
        c1 = dot2bf(ev.y, wp, c1);
        c2 = dot2bf(ev.z, wp, c2);
        c3 = dot2bf(ev.w, wp, c3);
      }
      *(float4*)&cpart[w][lane*4] = make_float4(c0,c1,c2,c3);
    }
    __syncthreads();
    if (q4 == 0){
      float cx = 0.f;
      #pragma unroll
      for (int i=0;i<16;i++) cx += cpart[i][d];
      float other = __shfl_xor(cx, 1);
      if ((d & 1) == 0) xb[d>>1] = pack2(cx, other);
      if (d == 128) xb[128] = pack2(xin[0], xin[1]);
      if (d == 129) xb[129] = pack2(xin[2], 0.f);
    }
    __syncthreads();

    // ---- G: gates (4-way K-split, dot2); quarters 0,1 = x-part, 2,3 = h-part ----
    {
      float ar=0.f, az=0.f, an=0.f;
      const int k0 = q4*65;
      const uint32_t* pk = PKq + (size_t)k0*768 + d;
      #pragma unroll 4
      for (int k2l=0; k2l<65; ++k2l){
        uint32_t xp = xb[k0 + k2l];
        ar = dot2bf(pk[0],   xp, ar);
        az = dot2bf(pk[256], xp, az);
        an = dot2bf(pk[512], xp, an);
        pk += 768;
      }
      gpart[q4*3+0][d] = ar;
      gpart[q4*3+1][d] = az;
      gpart[q4*3+2][d] = an;
    }
    __syncthreads();
    if (q4 == 0){
      float ar  = (gpart[0][d]+gpart[3][d]) + (gpart[6][d]+gpart[9][d]) + bias_r;
      float az  = (gpart[1][d]+gpart[4][d]) + (gpart[7][d]+gpart[10][d]) + bias_z;
      float ani = gpart[2][d] + gpart[5][d]  + bias_ni;
      float anh = gpart[8][d] + gpart[11][d] + bias_nh;
      float rg = sigm_f(ar);
      float zg = sigm_f(az);
      float ng = tanh_f(ani + rg*anh);
      float hnew = (1.f-zg)*ng + zg*hf[d];
      hf[d] = hnew;
      float other = __shfl_xor(hnew, 1);
      if ((d & 1) == 0) xb[130 + (d>>1)] = pack2(hnew, other);
    }
    __syncthreads();

    // ---- out projection (wave 0 only; overlaps next step's Q on other waves) ----
    if (w == 0){
      float p0=0,p1=0,p2=0;
      #pragma unroll
      for (int i=0;i<4;i++){
        float hv = hf[i*64 + lane];
        p0 = fmaf(hv, WoL[      i*64+lane], p0);
        p1 = fmaf(hv, WoL[256 + i*64+lane], p1);
        p2 = fmaf(hv, WoL[512 + i*64+lane], p2);
      }
      #pragma unroll
      for (int o=32;o;o>>=1){
        p0+=__shfl_xor(p0,o); p1+=__shfl_xor(p1,o); p2+=__shfl_xor(p2,o);
      }
      if (lane==0){
        float o0=p0+bo0, o1=p1+bo1, o2=p2+bo2;
        __builtin_nontemporal_store(o0, &do_b[(size_t)step*NO+0]);
        __builtin_nontemporal_store(o1, &do_b[(size_t)step*NO+1]);
        __builtin_nontemporal_store(o2, &do_b[(size_t)step*NO+2]);
        xin[0]=o0; xin[1]=o1; xin[2]=o2;
      }
    }
    // no barrier needed here: next step's first barrier orders xin/hf consumers
  }

  __syncthreads();
  if (q4 == 0) hT_out[(size_t)b*ND + d] = hf[d];
}

// ---------------- host launch ----------------

extern "C" void kernel_launch(void* const* d_in, const int* in_sizes, int n_in,
                              void* d_out, int out_size, void* d_ws, size_t ws_size,
                              hipStream_t stream) {
  const float* e_all  = (const float*)d_in[0];
  const float* e_last = (const float*)d_in[1];
  const float* Wa     = (const float*)d_in[2];
  const float* ba     = (const float*)d_in[3];
  const float* Ua     = (const float*)d_in[4];
  const float* bu     = (const float*)d_in[5];
  const float* Va     = (const float*)d_in[6];
  const float* bv     = (const float*)d_in[7];
  const float* W_ih   = (const float*)d_in[8];
  const float* b_ih   = (const float*)d_in[9];
  const float* W_hh   = (const float*)d_in[10];
  const float* b_hh   = (const float*)d_in[11];
  const float* Wo     = (const float*)d_in[12];
  const float* bo     = (const float*)d_in[13];

  // workspace layout (~135.1 MB, within previously-working footprint)
  char* ws = (char*)d_ws;
  uint16_t* UK   = (uint16_t*)(ws + 0ull);           // bf16 [B][D/4][S][4]   67108864 B
  uint32_t* EP   = (uint32_t*)(ws + 67108864ull);    // u32  [B][128][256]    67108864 B
  // region A: first UaT (prep-only), then overwritten by PKq after k_uk (stream-ordered)
  float*    UaT  = (float*)(ws + 134217728ull);      // f32 [256][256]          262144 B
  uint32_t* PKq  = (uint32_t*)(ws + 134217728ull);   // u32 [260][3][256]       798720 B
  uint32_t* PQ   = (uint32_t*)(ws + 135016448ull);   // u32 [128][256]          131072 B

  float* dout = (float*)d_out;                       // [B][T][3]
  float* hT   = dout + (size_t)NB*NT*NO;             // [B][D]
  float* ca   = hT   + (size_t)NB*ND;                // [B][T*S]

  // prep (stream order guarantees UaT consumed by k_uk before k_pkq overwrites)
  k_transpose<<<(ND*ND+255)/256,256,0,stream>>>(Ua, UaT, ND, ND);
  k_uk<<<NB*NS/16,256,0,stream>>>(e_all, UaT, bu, UK);
  k_ep<<<(NB*128*256+255)/256,256,0,stream>>>(e_all, EP);
  k_pkq<<<(260*3*256+255)/256,256,0,stream>>>(W_ih, W_hh, PKq);
  k_pack_q<<<(128*256+255)/256,256,0,stream>>>(Wa, PQ);

  // persistent decode: 512 blocks x 1024 threads = 2 blocks/CU, 32 waves/CU
  k_decode<<<NB,1024,0,stream>>>(UK, EP, PKq, PQ, e_last, Va, bv,
                                 b_ih, b_hh, ba, bo, Wo, dout, hT, ca);
}

// Round 4
// 7737.652 us; speedup vs baseline: 2.5012x; 2.5012x over previous
//
#include <hip/hip_runtime.h>
#include <hip/hip_bf16.h>
#include <stdint.h>

// Problem sizes (fixed)
#define NB 512     // batch
#define NS 256     // source length
#define ND 256     // hidden dim
#define NT 256     // decode steps
#define NO 3       // output dim

#define LOG2E 1.44269504088896340736f
#define C2 (2.0f*LOG2E)

#if __has_builtin(__builtin_amdgcn_exp2f)
__device__ __forceinline__ float exp2_fast(float x){ return __builtin_amdgcn_exp2f(x); }
#else
__device__ __forceinline__ float exp2_fast(float x){ return exp2f(x); }
#endif
#if __has_builtin(__builtin_amdgcn_rcpf)
__device__ __forceinline__ float rcp_fast(float x){ return __builtin_amdgcn_rcpf(x); }
#else
__device__ __forceinline__ float rcp_fast(float x){ return 1.0f/x; }
#endif

__device__ __forceinline__ float tanh_f(float x){
  float e = exp2_fast(x * C2);
  return 1.0f - 2.0f*rcp_fast(e + 1.0f);
}
__device__ __forceinline__ float sigm_f(float x){
  return rcp_fast(1.0f + exp2_fast(-x*LOG2E));
}
__device__ __forceinline__ float bflo(uint32_t u){ return __uint_as_float(u<<16); }
__device__ __forceinline__ float bfhi(uint32_t u){ return __uint_as_float(u & 0xffff0000u); }
__device__ __forceinline__ uint16_t f2bf(float f){   // round-to-nearest-even bf16
  uint32_t u = __float_as_uint(f);
  return (uint16_t)((u + 0x7fffu + ((u>>16)&1u)) >> 16);
}
__device__ __forceinline__ uint32_t pack2(float a, float b){
  return (uint32_t)f2bf(a) | ((uint32_t)f2bf(b) << 16);
}

// bf16-pair dot product: c + a.lo*b.lo + a.hi*b.hi
#if __has_builtin(__builtin_amdgcn_fdot2_f32_bf16)
typedef __bf16 bfp2 __attribute__((ext_vector_type(2)));
__device__ __forceinline__ float dot2bf(uint32_t a, uint32_t b, float c){
  return __builtin_amdgcn_fdot2_f32_bf16(__builtin_bit_cast(bfp2, a),
                                         __builtin_bit_cast(bfp2, b), c, false);
}
#else
__device__ __forceinline__ float dot2bf(uint32_t a, uint32_t b, float c){
  return c + bflo(a)*bflo(b) + bfhi(a)*bfhi(b);
}
#endif

// ---------------- prep kernels ----------------

// dst[c*R + r] = src[r*C + c]
__global__ void k_transpose(const float* __restrict__ src, float* __restrict__ dst,
                            int R, int C){
  int idx = blockIdx.x*256 + threadIdx.x;
  if (idx < R*C){
    int r = idx / C, c = idx - r*C;
    dst[c*R + r] = src[idx];
  }
}

// UK8[b][e8][s][8] (bf16, d-interleaved-by-8, PRE-SCALED by 2*log2e)
__global__ void __launch_bounds__(256) k_uk(const float* __restrict__ e_all,
    const float* __restrict__ UaT, const float* __restrict__ bu,
    uint16_t* __restrict__ UK){
  __shared__ float At[ND][20];
  const int t = threadIdx.x;
  const int m0 = blockIdx.x * 16;
  const int b  = m0 >> 8;
  const int s0 = m0 & (NS-1);
  #pragma unroll
  for (int i=0;i<16;i++)
    At[t][i] = e_all[(size_t)(m0+i)*ND + t];
  __syncthreads();
  float acc[16];
  float bue = bu[t];
  #pragma unroll
  for (int i=0;i<16;i++) acc[i] = bue;
  for (int d=0; d<ND; ++d){
    float u = UaT[d*ND + t];
    const float4 a0 = *(const float4*)&At[d][0];
    const float4 a1 = *(const float4*)&At[d][4];
    const float4 a2 = *(const float4*)&At[d][8];
    const float4 a3 = *(const float4*)&At[d][12];
    acc[0]+=a0.x*u;  acc[1]+=a0.y*u;  acc[2]+=a0.z*u;  acc[3]+=a0.w*u;
    acc[4]+=a1.x*u;  acc[5]+=a1.y*u;  acc[6]+=a1.z*u;  acc[7]+=a1.w*u;
    acc[8]+=a2.x*u;  acc[9]+=a2.y*u;  acc[10]+=a2.z*u; acc[11]+=a2.w*u;
    acc[12]+=a3.x*u; acc[13]+=a3.y*u; acc[14]+=a3.z*u; acc[15]+=a3.w*u;
  }
  const int e8 = t>>3, j = t&7;
  uint16_t* base = UK + (size_t)b*NS*ND + (size_t)e8*(NS*8) + j;
  #pragma unroll
  for (int i=0;i<16;i++)
    base[(size_t)(s0+i)*8] = f2bf(acc[i] * C2);
}

// EP[b][s2][d] = {bf16 e[b][2s2][d], bf16 e[b][2s2+1][d]}
__global__ void k_ep(const float* __restrict__ e_all, uint32_t* __restrict__ EP){
  int idx = blockIdx.x*256 + threadIdx.x;
  if (idx >= NB*128*256) return;
  int d  = idx & 255;
  int s2 = (idx >> 8) & 127;
  int b  = idx >> 15;
  float e0 = e_all[((size_t)b*NS + 2*s2  )*ND + d];
  float e1 = e_all[((size_t)b*NS + 2*s2+1)*ND + d];
  EP[idx] = pack2(e0, e1);
}

// PKq[k2][g][d] u32 pairs over combined K-axis:
//   k2 in [0,130): x-part pairs {k=2k2, 2k2+1} of W_ih (k<259, else 0)
//   k2 in [130,258): h-part pairs of W_hh ; [258,260): zero pad
__global__ void k_pkq(const float* __restrict__ W_ih, const float* __restrict__ W_hh,
                      uint32_t* __restrict__ PKq){
  int idx = blockIdx.x*256 + threadIdx.x;   // ((k2*3)+g)*256 + d
  if (idx >= 260*3*256) return;
  int d  = idx & 255;
  int gk = idx >> 8;
  int k2 = gk/3, g = gk - 3*k2;
  int col = g*256 + d;
  float w0 = 0.f, w1 = 0.f;
  if (k2 < 130){
    int k0 = 2*k2, k1 = k0+1;
    w0 = W_ih[(size_t)col*259 + k0];
    w1 = (k1 < 259) ? W_ih[(size_t)col*259 + k1] : 0.f;
  } else if (k2 < 258){
    int kk = 2*(k2-130);
    w0 = W_hh[(size_t)col*256 + kk];
    w1 = W_hh[(size_t)col*256 + kk+1];
  }
  PKq[idx] = pack2(w0, w1);
}

// PQ[k2][d] = {bf16 Wa[d][2k2], bf16 Wa[d][2k2+1]}
__global__ void k_pack_q(const float* __restrict__ Wa, uint32_t* __restrict__ PQ){
  int idx = blockIdx.x*256 + threadIdx.x;   // k2*256 + d
  if (idx >= 128*256) return;
  int d = idx & 255, k2 = idx >> 8;
  PQ[idx] = pack2(Wa[(size_t)d*256 + 2*k2], Wa[(size_t)d*256 + 2*k2 + 1]);
}

// ---------------- persistent decode kernel ----------------
// 256 blocks x 1024 threads; TWO batch elements per block (weight reuse x2).
// t: d = t&255, q4 = t>>8, bi = q4>>1 (batch-in-block), half = q4&1.
__global__ void __launch_bounds__(1024, 4) k_decode(
    const uint16_t* __restrict__ UK, const uint32_t* __restrict__ EP,
    const uint32_t* __restrict__ PKq, const uint32_t* __restrict__ PQ,
    const float* __restrict__ e_last,
    const float* __restrict__ Va, const float* __restrict__ bv,
    const float* __restrict__ b_ih, const float* __restrict__ b_hh,
    const float* __restrict__ ba, const float* __restrict__ bo,
    const float* __restrict__ Wo,
    float* __restrict__ dout, float* __restrict__ hT_out, float* __restrict__ ca)
{
  __shared__ float    hf[2][ND];
  __shared__ float    xin[2][4];
  __shared__ uint32_t xb[2][260];           // bf16 pairs: [0..129]=ctx+x, [130..257]=h, pad
  __shared__ __align__(16) float qL[2][ND]; // pre-scaled q per batch
  __shared__ __align__(16) float va2[ND];   // 2*Va
  __shared__ float    WoL[3*ND];
  __shared__ float    qpart[2][2][ND];
  __shared__ float    spart[2][2][ND];
  __shared__ __align__(16) float cpart[2][8][ND];
  __shared__ float    gpart[2][4][3][ND];
  __shared__ uint32_t wb[2][128];
  __shared__ float    red[16];

  const int t    = threadIdx.x;
  const int d    = t & 255;
  const int q4   = t >> 8;
  const int bi   = q4 >> 1;
  const int half = q4 & 1;
  const int lane = t & 63;
  const int w    = t >> 6;
  const int b0   = blockIdx.x * 2;

  // ---- init ----
  if (q4 == 0){
    hf[0][d] = e_last[(size_t)b0*ND + d];
    va2[d]   = 2.0f*Va[d];
    WoL[d] = Wo[d]; WoL[256+d] = Wo[256+d]; WoL[512+d] = Wo[512+d];
    if (d < 4){ xin[0][d]=0.f; xin[1][d]=0.f; }
  } else if (q4 == 1){
    hf[1][d] = e_last[(size_t)(b0+1)*ND + d];
  }
  const float bias_r  = b_ih[d]     + b_hh[d];
  const float bias_z  = b_ih[256+d] + b_hh[256+d];
  const float bias_ni = b_ih[512+d];
  const float bias_nh = b_hh[512+d];
  const float ba_d = ba[d];
  const float bv0  = bv[0];
  const float bo0 = bo[0], bo1 = bo[1], bo2 = bo[2];
  __syncthreads();
  if (t < 256){
    int bb = t>>7, i = t&127;
    xb[bb][130+i] = pack2(hf[bb][2*i], hf[bb][2*i+1]);
  }
  if (t == 256){
    xb[0][128]=0u; xb[0][129]=0u; xb[0][258]=0u; xb[0][259]=0u;
    xb[1][128]=0u; xb[1][129]=0u; xb[1][258]=0u; xb[1][259]=0u;
  }
  float sumVaH = 0.f;
  {
    #pragma unroll 8
    for (int e = half*128; e < half*128+128; ++e) sumVaH += va2[e];
    sumVaH *= 0.5f;
  }
  __syncthreads();

  const uint16_t* ukb  = UK + (size_t)(b0+bi)*NS*ND + (size_t)half*16*2048 + (size_t)d*8;
  const uint32_t* epbw = EP + (size_t)(b0+(w>>3))*128*256;   // C-phase batch = w>>3
  float* ca_bq = ca + (size_t)(b0 + (q4&1))*(NT*NS);         // used when q4<2

  #pragma unroll 1
  for (int step=0; step<NT; ++step){
    // ---- Q: q = h @ Wa^T + ba ; split (batch bi) x (k-half) ----
    {
      float aq = 0.f;
      const uint32_t* pq = PQ + (size_t)(half*64)*256 + d;
      const uint32_t* xh = &xb[bi][130 + half*64];
      #pragma unroll 1
      for (int kk=0; kk<64; kk+=8){
        uint32_t wv[8], xv[8];
        #pragma unroll
        for (int j=0;j<8;j++){ wv[j] = pq[(kk+j)*256]; xv[j] = xh[kk+j]; }
        #pragma unroll
        for (int j=0;j<8;j++) aq = dot2bf(wv[j], xv[j], aq);
      }
      qpart[bi][half][d] = aq;
    }
    __syncthreads();
    if (q4 < 2)
      qL[q4][d] = (qpart[q4][0][d] + qpart[q4][1][d] + ba_d) * C2;
    __syncthreads();

    // ---- S: scores for (batch bi, s=d, e-half) ; folded tanh ----
    {
      float acc = 0.f;
      #pragma unroll 1
      for (int g=0; g<16; g+=8){
        uint4 u[8];
        #pragma unroll
        for (int j=0;j<8;j++) u[j] = *(const uint4*)(ukb + (size_t)(g+j)*2048);
        #pragma unroll
        for (int j=0;j<8;j++){
          const int e0 = half*128 + (g+j)*8;
          const float4 q0 = *(const float4*)&qL[bi][e0];
          const float4 q1 = *(const float4*)&qL[bi][e0+4];
          const float4 v0 = *(const float4*)&va2[e0];
          const float4 v1 = *(const float4*)&va2[e0+4];
          float r;
          r = rcp_fast(exp2_fast(bflo(u[j].x)+q0.x)+1.f); acc = fmaf(v0.x, r, acc);
          r = rcp_fast(exp2_fast(bfhi(u[j].x)+q0.y)+1.f); acc = fmaf(v0.y, r, acc);
          r = rcp_fast(exp2_fast(bflo(u[j].y)+q0.z)+1.f); acc = fmaf(v0.z, r, acc);
          r = rcp_fast(exp2_fast(bfhi(u[j].y)+q0.w)+1.f); acc = fmaf(v0.w, r, acc);
          r = rcp_fast(exp2_fast(bflo(u[j].z)+q1.x)+1.f); acc = fmaf(v1.x, r, acc);
          r = rcp_fast(exp2_fast(bfhi(u[j].z)+q1.y)+1.f); acc = fmaf(v1.y, r, acc);
          r = rcp_fast(exp2_fast(bflo(u[j].w)+q1.z)+1.f); acc = fmaf(v1.z, r, acc);
          r = rcp_fast(exp2_fast(bfhi(u[j].w)+q1.w)+1.f); acc = fmaf(v1.w, r, acc);
        }
      }
      spart[bi][half][d] = sumVaH - acc;
    }
    __syncthreads();

    // ---- softmax (no max-subtract; |score| <= sum|Va|+|bv| is small) ----
    float p_reg = 0.f;
    if (q4 < 2){
      float sc = spart[q4][0][d] + spart[q4][1][d] + bv0;
      p_reg = exp2_fast(sc * LOG2E);
      float ssum = p_reg;
      #pragma unroll
      for (int o=32;o;o>>=1) ssum += __shfl_xor(ssum, o);
      if (lane==0) red[w] = ssum;      // waves 0-3 (batch0), 4-7 (batch1)
    }
    __syncthreads();
    if (q4 < 2){
      const int rb = q4*4;
      float ssum = (red[rb]+red[rb+1]) + (red[rb+2]+red[rb+3]);
      float wgt = p_reg * rcp_fast(ssum);
      __builtin_nontemporal_store(wgt, &ca_bq[(size_t)step*NS + d]);
      float other = __shfl_xor(wgt, 1);
      if (!(d&1)) wb[q4][d>>1] = pack2(wgt, other);
    }
    __syncthreads();

    // ---- C: ctx ; wave w -> (batch w>>3, s2-range (w&7)*16..+16) ----
    {
      const int cb = w>>3, sub = w&7;
      float c0=0,c1=0,c2=0,c3=0;
      const int s0 = sub*16;
      #pragma unroll 1
      for (int g=0; g<16; g+=8){
        uint4 ev[8]; uint32_t wp[8];
        #pragma unroll
        for (int j=0;j<8;j++){
          ev[j] = *(const uint4*)(epbw + (size_t)(s0+g+j)*256 + lane*4);
          wp[j] = wb[cb][s0+g+j];
        }
        #pragma unroll
        for (int j=0;j<8;j++){
          c0 = dot2bf(ev[j].x, wp[j], c0);
          c1 = dot2bf(ev[j].y, wp[j], c1);
          c2 = dot2bf(ev[j].z, wp[j], c2);
          c3 = dot2bf(ev[j].w, wp[j], c3);
        }
      }
      *(float4*)&cpart[cb][sub][lane*4] = make_float4(c0,c1,c2,c3);
    }
    __syncthreads();
    if (q4 < 2){
      float cx = 0.f;
      #pragma unroll
      for (int i=0;i<8;i++) cx += cpart[q4][i][d];
      float other = __shfl_xor(cx, 1);
      if (!(d&1)) xb[q4][d>>1] = pack2(cx, other);
      if (d==128) xb[q4][128] = pack2(xin[q4][0], xin[q4][1]);
      if (d==129) xb[q4][129] = pack2(xin[q4][2], 0.f);
    }
    __syncthreads();

    // ---- G: gates ; quarter q4 = k2-quarter, BOTH batches per weight load ----
    {
      float a0r=0,a0z=0,a0n=0, a1r=0,a1z=0,a1n=0;
      const int k0 = q4*65;
      const uint32_t* pk = PKq + (size_t)k0*768 + d;
      #pragma unroll 1
      for (int g=0; g<64; g+=8){
        uint32_t wr[8], wz[8], wn[8], x0[8], x1[8];
        #pragma unroll
        for (int j=0;j<8;j++){
          const uint32_t* p = pk + (size_t)(g+j)*768;
          wr[j]=p[0]; wz[j]=p[256]; wn[j]=p[512];
          x0[j]=xb[0][k0+g+j]; x1[j]=xb[1][k0+g+j];
        }
        #pragma unroll
        for (int j=0;j<8;j++){
          a0r=dot2bf(wr[j],x0[j],a0r); a0z=dot2bf(wz[j],x0[j],a0z); a0n=dot2bf(wn[j],x0[j],a0n);
          a1r=dot2bf(wr[j],x1[j],a1r); a1z=dot2bf(wz[j],x1[j],a1z); a1n=dot2bf(wn[j],x1[j],a1n);
        }
      }
      { // last k2 (65th)
        const uint32_t* p = pk + (size_t)64*768;
        uint32_t w0=p[0], w1=p[256], w2=p[512];
        uint32_t xa=xb[0][k0+64], xc=xb[1][k0+64];
        a0r=dot2bf(w0,xa,a0r); a0z=dot2bf(w1,xa,a0z); a0n=dot2bf(w2,xa,a0n);
        a1r=dot2bf(w0,xc,a1r); a1z=dot2bf(w1,xc,a1z); a1n=dot2bf(w2,xc,a1n);
      }
      gpart[0][q4][0][d]=a0r; gpart[0][q4][1][d]=a0z; gpart[0][q4][2][d]=a0n;
      gpart[1][q4][0][d]=a1r; gpart[1][q4][1][d]=a1z; gpart[1][q4][2][d]=a1n;
    }
    __syncthreads();
    if (q4 < 2){
      float ar  = (gpart[q4][0][0][d]+gpart[q4][1][0][d]) + (gpart[q4][2][0][d]+gpart[q4][3][0][d]) + bias_r;
      float az  = (gpart[q4][0][1][d]+gpart[q4][1][1][d]) + (gpart[q4][2][1][d]+gpart[q4][3][1][d]) + bias_z;
      float ani =  gpart[q4][0][2][d]+gpart[q4][1][2][d] + bias_ni;   // x-part (k2<130)
      float anh =  gpart[q4][2][2][d]+gpart[q4][3][2][d] + bias_nh;   // h-part
      float rg = sigm_f(ar);
      float zg = sigm_f(az);
      float ng = tanh_f(ani + rg*anh);
      float hnew = (1.f-zg)*ng + zg*hf[q4][d];
      hf[q4][d] = hnew;
      float other = __shfl_xor(hnew, 1);
      if (!(d&1)) xb[q4][130 + (d>>1)] = pack2(hnew, other);
    }
    __syncthreads();

    // ---- out projection: waves 0 (batch0) and 8 (batch1) ----
    if ((w & 7) == 0){
      const int bq = w >> 3;
      float p0=0,p1=0,p2=0;
      #pragma unroll
      for (int i=0;i<4;i++){
        float hv = hf[bq][i*64 + lane];
        p0 = fmaf(hv, WoL[      i*64+lane], p0);
        p1 = fmaf(hv, WoL[256 + i*64+lane], p1);
        p2 = fmaf(hv, WoL[512 + i*64+lane], p2);
      }
      #pragma unroll
      for (int o=32;o;o>>=1){
        p0+=__shfl_xor(p0,o); p1+=__shfl_xor(p1,o); p2+=__shfl_xor(p2,o);
      }
      if (lane==0){
        float o0=p0+bo0, o1=p1+bo1, o2=p2+bo2;
        float* do_b = dout + (size_t)(b0+bq)*(NT*NO);
        __builtin_nontemporal_store(o0, &do_b[(size_t)step*NO+0]);
        __builtin_nontemporal_store(o1, &do_b[(size_t)step*NO+1]);
        __builtin_nontemporal_store(o2, &do_b[(size_t)step*NO+2]);
        xin[bq][0]=o0; xin[bq][1]=o1; xin[bq][2]=o2;
      }
    }
    // next step's barriers order xin/hf consumers
  }

  __syncthreads();
  if (q4 < 2) hT_out[(size_t)(b0+q4)*ND + d] = hf[q4][d];
}

// ---------------- host launch ----------------

extern "C" void kernel_launch(void* const* d_in, const int* in_sizes, int n_in,
                              void* d_out, int out_size, void* d_ws, size_t ws_size,
                              hipStream_t stream) {
  const float* e_all  = (const float*)d_in[0];
  const float* e_last = (const float*)d_in[1];
  const float* Wa     = (const float*)d_in[2];
  const float* ba     = (const float*)d_in[3];
  const float* Ua     = (const float*)d_in[4];
  const float* bu     = (const float*)d_in[5];
  const float* Va     = (const float*)d_in[6];
  const float* bv     = (const float*)d_in[7];
  const float* W_ih   = (const float*)d_in[8];
  const float* b_ih   = (const float*)d_in[9];
  const float* W_hh   = (const float*)d_in[10];
  const float* b_hh   = (const float*)d_in[11];
  const float* Wo     = (const float*)d_in[12];
  const float* bo     = (const float*)d_in[13];

  // workspace layout (~135.1 MB)
  char* ws = (char*)d_ws;
  uint16_t* UK   = (uint16_t*)(ws + 0ull);           // bf16 [B][D/8][S][8]   67108864 B
  uint32_t* EP   = (uint32_t*)(ws + 67108864ull);    // u32  [B][128][256]    67108864 B
  // region A: first UaT (prep-only), then overwritten by PKq after k_uk (stream-ordered)
  float*    UaT  = (float*)(ws + 134217728ull);      // f32 [256][256]          262144 B
  uint32_t* PKq  = (uint32_t*)(ws + 134217728ull);   // u32 [260][3][256]       798720 B
  uint32_t* PQ   = (uint32_t*)(ws + 135016448ull);   // u32 [128][256]          131072 B

  float* dout = (float*)d_out;                       // [B][T][3]
  float* hT   = dout + (size_t)NB*NT*NO;             // [B][D]
  float* ca   = hT   + (size_t)NB*ND;                // [B][T*S]

  // prep (stream order: UaT consumed by k_uk before k_pkq overwrites region A)
  k_transpose<<<(ND*ND+255)/256,256,0,stream>>>(Ua, UaT, ND, ND);
  k_uk<<<NB*NS/16,256,0,stream>>>(e_all, UaT, bu, UK);
  k_ep<<<(NB*128*256+255)/256,256,0,stream>>>(e_all, EP);
  k_pkq<<<(260*3*256+255)/256,256,0,stream>>>(W_ih, W_hh, PKq);
  k_pack_q<<<(128*256+255)/256,256,0,stream>>>(Wa, PQ);

  // persistent decode: 256 blocks x 1024 threads, 2 batch elements per block
  k_decode<<<NB/2,1024,0,stream>>>(UK, EP, PKq, PQ, e_last, Va, bv,
                                   b_ih, b_hh, ba, bo, Wo, dout, hT, ca);
}